// Round 1
// baseline (438.170 us; speedup 1.0000x reference)
//
#include <hip/hip_runtime.h>

// Problem constants (from reference): B=64, S=1024, H=1000.
constexpr int Bb = 64;
constexpr int Ss = 1024;
constexpr int Hh = 1000;
constexpr int CHUNKS = 32;          // s-chunks per batch (one wave each)
constexpr int CS = Ss / CHUNKS;     // 32 positions per wave

// Kernel 1: u[b,h] = sum_g h_tgt[b,g] * W[g,h]   (tiny GEMV batch; W is 4 MB, L2-resident)
__global__ __launch_bounds__(256) void proj_tgt_kernel(
    const float* __restrict__ h_tgt, const float* __restrict__ W,
    float* __restrict__ u)
{
    const int h = blockIdx.x * blockDim.x + threadIdx.x;
    const int b = blockIdx.y;
    if (h >= Hh) return;
    const float* ht = h_tgt + b * Hh;   // scalar (wave-uniform) loads
    float acc = 0.f;
    #pragma unroll 8
    for (int g = 0; g < Hh; ++g)
        acc = fmaf(ht[g], W[g * Hh + h], acc);  // W read coalesced across h
    u[b * Hh + h] = acc;
}

// Kernel 2: fused score + online softmax + weighted accumulation.
// One wave per (b, s-chunk). h_src is read exactly ONCE (262 MB total).
__global__ __launch_bounds__(256) void attn_partial_kernel(
    const float* __restrict__ h_src, const float* __restrict__ u,
    float* __restrict__ wsM, float* __restrict__ wsL, float* __restrict__ wsC)
{
    const int lane  = threadIdx.x & 63;
    const int wave  = (int)((blockIdx.x * blockDim.x + threadIdx.x) >> 6);
    const int b     = wave / CHUNKS;
    const int chunk = wave % CHUNKS;
    const int s0    = chunk * CS;

    // u fragment: lane covers dims {j*256 + 4*lane .. +3}, j=0..3 (1000 = 250 float4s)
    const float* ub = u + b * Hh;
    float4 uf[4];
    #pragma unroll
    for (int j = 0; j < 4; ++j) {
        const int d = j * 256 + lane * 4;
        uf[j] = (d < Hh) ? *(const float4*)(ub + d) : make_float4(0.f, 0.f, 0.f, 0.f);
    }

    float m = -INFINITY, l = 0.f;
    float4 c[4];
    #pragma unroll
    for (int j = 0; j < 4; ++j) c[j] = make_float4(0.f, 0.f, 0.f, 0.f);

    const float* xp = h_src + (size_t)(b * Ss + s0) * Hh;
    for (int s = 0; s < CS; ++s) {
        float4 x[4];
        #pragma unroll
        for (int j = 0; j < 4; ++j) {
            const int d = j * 256 + lane * 4;
            x[j] = (d < Hh) ? *(const float4*)(xp + d) : make_float4(0.f, 0.f, 0.f, 0.f);
        }
        // partial dot
        float part = 0.f;
        #pragma unroll
        for (int j = 0; j < 4; ++j) {
            part = fmaf(x[j].x, uf[j].x, part);
            part = fmaf(x[j].y, uf[j].y, part);
            part = fmaf(x[j].z, uf[j].z, part);
            part = fmaf(x[j].w, uf[j].w, part);
        }
        // 64-lane butterfly reduce -> identical score on every lane
        #pragma unroll
        for (int off = 32; off > 0; off >>= 1)
            part += __shfl_xor(part, off, 64);
        const float score = part;

        // online softmax; branch is wave-uniform (score identical across lanes)
        if (score > m) {
            const float scale = __expf(m - score);   // first iter: exp(-inf)=0 zeroes l,c
            m = score;
            l *= scale;
            #pragma unroll
            for (int j = 0; j < 4; ++j) {
                c[j].x *= scale; c[j].y *= scale; c[j].z *= scale; c[j].w *= scale;
            }
        }
        const float p = __expf(score - m);
        l += p;
        #pragma unroll
        for (int j = 0; j < 4; ++j) {
            c[j].x = fmaf(p, x[j].x, c[j].x);
            c[j].y = fmaf(p, x[j].y, c[j].y);
            c[j].z = fmaf(p, x[j].z, c[j].z);
            c[j].w = fmaf(p, x[j].w, c[j].w);
        }
        xp += Hh;
    }

    const int idx = b * CHUNKS + chunk;
    if (lane == 0) { wsM[idx] = m; wsL[idx] = l; }
    float* cw = wsC + (size_t)idx * Hh;
    #pragma unroll
    for (int j = 0; j < 4; ++j) {
        const int d = j * 256 + lane * 4;
        if (d < Hh) *(float4*)(cw + d) = c[j];
    }
}

// Kernel 3: merge the 32 chunk-partials per batch. Reads ~8 MB.
__global__ __launch_bounds__(256) void combine_kernel(
    const float* __restrict__ wsM, const float* __restrict__ wsL,
    const float* __restrict__ wsC, float* __restrict__ out)
{
    const int b = blockIdx.x;
    __shared__ float sw[CHUNKS];
    __shared__ float sInvL;
    if (threadIdx.x == 0) {
        float M = -INFINITY;
        for (int i = 0; i < CHUNKS; ++i) M = fmaxf(M, wsM[b * CHUNKS + i]);
        float L = 0.f;
        for (int i = 0; i < CHUNKS; ++i) {
            const float e = __expf(wsM[b * CHUNKS + i] - M);
            sw[i] = e;
            L = fmaf(e, wsL[b * CHUNKS + i], L);
        }
        sInvL = 1.f / L;
    }
    __syncthreads();
    for (int h = (int)threadIdx.x; h < Hh; h += (int)blockDim.x) {
        float acc = 0.f;
        #pragma unroll 8
        for (int i = 0; i < CHUNKS; ++i)
            acc = fmaf(sw[i], wsC[(size_t)(b * CHUNKS + i) * Hh + h], acc);
        out[b * Hh + h] = acc * sInvL;
    }
}

extern "C" void kernel_launch(void* const* d_in, const int* in_sizes, int n_in,
                              void* d_out, int out_size, void* d_ws, size_t ws_size,
                              hipStream_t stream) {
    const float* h_tgt = (const float*)d_in[0];
    const float* h_src = (const float*)d_in[1];
    const float* W     = (const float*)d_in[2];
    // d_in[3] (bias) is unused: h_tgt·bias is constant over s and cancels in softmax.
    float* out = (float*)d_out;

    // workspace layout (floats): u[64000] | wsM[2048] | wsL[2048] | wsC[2048000]  (~8.5 MB)
    float* u   = (float*)d_ws;
    float* wsM = u + Bb * Hh;
    float* wsL = wsM + Bb * CHUNKS;
    float* wsC = wsL + Bb * CHUNKS;   // byte offset 272384, 16B-aligned for float4

    proj_tgt_kernel<<<dim3((Hh + 255) / 256, Bb), 256, 0, stream>>>(h_tgt, W, u);
    attn_partial_kernel<<<(Bb * CHUNKS) / 4, 256, 0, stream>>>(h_src, u, wsM, wsL, wsC);
    combine_kernel<<<Bb, 256, 0, stream>>>(wsM, wsL, wsC, out);
}

// Round 2
// 429.764 us; speedup vs baseline: 1.0196x; 1.0196x over previous
//
#include <hip/hip_runtime.h>

// Problem constants: B=64, S=1024, H=1000.
constexpr int Bb = 64;
constexpr int Ss = 1024;
constexpr int Hh = 1000;
constexpr int CHUNKS = 64;          // s-chunks per batch (one wave each)
constexpr int CS = Ss / CHUNKS;     // 16 positions per wave
constexpr int BG = 4;               // batches per proj block
constexpr int GQ = 4;               // g-quarters per proj block (250 g each)

// Kernel 1: u[b,h] = sum_g h_tgt[b,g] * W[g,h]
// Block: 64-wide h-slice x BG batches; 4 waves split g into quarters, LDS-reduce.
// W cache traffic: 16 b-groups x 4 MB = 64 MB (vs 256 MB before).
__global__ __launch_bounds__(256) void proj_tgt_kernel(
    const float* __restrict__ h_tgt, const float* __restrict__ W,
    float* __restrict__ u)
{
    const int hl = threadIdx.x & 63;
    const int gq = threadIdx.x >> 6;          // 0..3 (wave-uniform)
    const int h  = blockIdx.x * 64 + hl;
    const int b0 = blockIdx.y * BG;
    const bool hok = (h < Hh);

    float acc[BG] = {0.f, 0.f, 0.f, 0.f};
    const int g0 = gq * (Hh / GQ);            // 250 g per quarter
    const int g1 = g0 + (Hh / GQ);
    #pragma unroll 2
    for (int g = g0; g < g1; ++g) {
        const float w = hok ? W[g * Hh + h] : 0.f;   // coalesced across hl
        #pragma unroll
        for (int bi = 0; bi < BG; ++bi)
            acc[bi] = fmaf(h_tgt[(b0 + bi) * Hh + g], w, acc[bi]);  // scalar loads
    }

    __shared__ float red[GQ][BG][64];
    #pragma unroll
    for (int bi = 0; bi < BG; ++bi) red[gq][bi][hl] = acc[bi];
    __syncthreads();
    if (gq == 0 && hok) {
        #pragma unroll
        for (int bi = 0; bi < BG; ++bi) {
            const float s = red[0][bi][hl] + red[1][bi][hl]
                          + red[2][bi][hl] + red[3][bi][hl];
            u[(b0 + bi) * Hh + h] = s;
        }
    }
}

// Kernel 2: fused score + online softmax + weighted accumulation.
// One wave per (b, s-chunk of 16); 4096 waves (16/CU). Two s-rows per
// iteration -> two independent dot/reduce/exp chains, 8 dwordx4 loads in flight.
__global__ __launch_bounds__(256) void attn_partial_kernel(
    const float* __restrict__ h_src, const float* __restrict__ u,
    float* __restrict__ wsM, float* __restrict__ wsL, float* __restrict__ wsC)
{
    const int lane  = threadIdx.x & 63;
    const int wave  = (int)((blockIdx.x * blockDim.x + threadIdx.x) >> 6);
    const int b     = wave >> 6;      // / CHUNKS
    const int chunk = wave & 63;      // % CHUNKS
    const int s0    = chunk * CS;

    const float* ub = u + b * Hh;
    float4 uf[4];
    #pragma unroll
    for (int j = 0; j < 4; ++j) {
        const int d = j * 256 + lane * 4;
        uf[j] = (d < Hh) ? *(const float4*)(ub + d) : make_float4(0.f, 0.f, 0.f, 0.f);
    }

    float m = -INFINITY, l = 0.f;
    float4 c[4];
    #pragma unroll
    for (int j = 0; j < 4; ++j) c[j] = make_float4(0.f, 0.f, 0.f, 0.f);

    const float* xp = h_src + (size_t)(b * Ss + s0) * Hh;
    #pragma unroll 2
    for (int s = 0; s < CS; s += 2) {
        float4 x0[4], x1[4];
        #pragma unroll
        for (int j = 0; j < 4; ++j) {
            const int d = j * 256 + lane * 4;
            x0[j] = (d < Hh) ? *(const float4*)(xp + d)      : make_float4(0.f,0.f,0.f,0.f);
            x1[j] = (d < Hh) ? *(const float4*)(xp + Hh + d) : make_float4(0.f,0.f,0.f,0.f);
        }
        float p0 = 0.f, p1 = 0.f;
        #pragma unroll
        for (int j = 0; j < 4; ++j) {
            p0 = fmaf(x0[j].x, uf[j].x, p0); p0 = fmaf(x0[j].y, uf[j].y, p0);
            p0 = fmaf(x0[j].z, uf[j].z, p0); p0 = fmaf(x0[j].w, uf[j].w, p0);
            p1 = fmaf(x1[j].x, uf[j].x, p1); p1 = fmaf(x1[j].y, uf[j].y, p1);
            p1 = fmaf(x1[j].z, uf[j].z, p1); p1 = fmaf(x1[j].w, uf[j].w, p1);
        }
        // two independent 64-lane butterflies (pipelined)
        #pragma unroll
        for (int off = 32; off > 0; off >>= 1) {
            p0 += __shfl_xor(p0, off, 64);
            p1 += __shfl_xor(p1, off, 64);
        }
        const float sc0 = p0, sc1 = p1;

        const float mn = fmaxf(m, fmaxf(sc0, sc1));
        if (mn > m) {                       // wave-uniform branch, rare
            const float scale = __expf(m - mn);  // first iter: exp(-inf)=0 zeroes l,c
            m = mn;
            l *= scale;
            #pragma unroll
            for (int j = 0; j < 4; ++j) {
                c[j].x *= scale; c[j].y *= scale; c[j].z *= scale; c[j].w *= scale;
            }
        }
        const float e0 = __expf(sc0 - m);
        const float e1 = __expf(sc1 - m);
        l += e0 + e1;
        #pragma unroll
        for (int j = 0; j < 4; ++j) {
            c[j].x = fmaf(e0, x0[j].x, fmaf(e1, x1[j].x, c[j].x));
            c[j].y = fmaf(e0, x0[j].y, fmaf(e1, x1[j].y, c[j].y));
            c[j].z = fmaf(e0, x0[j].z, fmaf(e1, x1[j].z, c[j].z));
            c[j].w = fmaf(e0, x0[j].w, fmaf(e1, x1[j].w, c[j].w));
        }
        xp += 2 * Hh;
    }

    const int idx = b * CHUNKS + chunk;
    if (lane == 0) { wsM[idx] = m; wsL[idx] = l; }
    float* cw = wsC + (size_t)idx * Hh;
    #pragma unroll
    for (int j = 0; j < 4; ++j) {
        const int d = j * 256 + lane * 4;
        if (d < Hh) *(float4*)(cw + d) = c[j];
    }
}

// Kernel 3: merge 64 chunk-partials per batch. Grid (64 b, 4 h-quarters).
__global__ __launch_bounds__(256) void combine_kernel(
    const float* __restrict__ wsM, const float* __restrict__ wsL,
    const float* __restrict__ wsC, float* __restrict__ out)
{
    const int b   = blockIdx.x;
    const int tid = (int)threadIdx.x;
    __shared__ float sw[CHUNKS];
    __shared__ float sInvL;

    if (tid < 64) {   // wave 0: lane = chunk; parallel max & weighted-l reduce
        const float mi = wsM[b * CHUNKS + tid];
        const float li = wsL[b * CHUNKS + tid];
        float M = mi;
        #pragma unroll
        for (int off = 32; off > 0; off >>= 1) M = fmaxf(M, __shfl_xor(M, off, 64));
        const float w = __expf(mi - M);
        float L = w * li;
        #pragma unroll
        for (int off = 32; off > 0; off >>= 1) L += __shfl_xor(L, off, 64);
        sw[tid] = w;
        if (tid == 0) sInvL = 1.f / L;
    }
    __syncthreads();

    const int h = blockIdx.y * 250 + tid;   // 4 quarters of 250 cover Hh=1000
    if (tid < 250) {
        float acc = 0.f;
        #pragma unroll 8
        for (int i = 0; i < CHUNKS; ++i)
            acc = fmaf(sw[i], wsC[(size_t)(b * CHUNKS + i) * Hh + h], acc);
        out[b * Hh + h] = acc * sInvL;
    }
}

extern "C" void kernel_launch(void* const* d_in, const int* in_sizes, int n_in,
                              void* d_out, int out_size, void* d_ws, size_t ws_size,
                              hipStream_t stream) {
    const float* h_tgt = (const float*)d_in[0];
    const float* h_src = (const float*)d_in[1];
    const float* W     = (const float*)d_in[2];
    // bias (d_in[3]) unused: h_tgt . bias is constant over s -> cancels in softmax.
    float* out = (float*)d_out;

    // workspace (floats): u[64000] | wsM[4096] | wsL[4096] | wsC[4096000] (~16.7 MB)
    float* u   = (float*)d_ws;
    float* wsM = u + Bb * Hh;
    float* wsL = wsM + Bb * CHUNKS;
    float* wsC = wsL + Bb * CHUNKS;   // float offset 72192 -> 16B aligned

    proj_tgt_kernel<<<dim3((Hh + 63) / 64, Bb / BG), 256, 0, stream>>>(h_tgt, W, u);
    attn_partial_kernel<<<(Bb * CHUNKS) / 4, 256, 0, stream>>>(h_src, u, wsM, wsL, wsC);
    combine_kernel<<<dim3(Bb, 4), 256, 0, stream>>>(wsM, wsL, wsC, out);
}

// Round 3
// 382.963 us; speedup vs baseline: 1.1442x; 1.1222x over previous
//
#include <hip/hip_runtime.h>

typedef float v4f __attribute__((ext_vector_type(4)));

// Problem constants: B=64, S=1024, H=1000.
constexpr int Bb = 64;
constexpr int Ss = 1024;
constexpr int Hh = 1000;
constexpr int CHUNKS = 64;          // s-chunks per batch (one wave each)
constexpr int CS = Ss / CHUNKS;     // 16 positions per wave
constexpr int BG = 4;               // batches per proj block
constexpr int GS = 8;               // g-splits for proj
constexpr int GL = Hh / GS;         // 125 g per split

// Kernel 1a: partial u. Grid (16 b-groups, 4 slot-groups, 8 g-splits) x 64 thr.
// Thread owns one float4 h-slot for 4 batches; streams 125 coalesced W rows.
// u_part[p][b][h] (2 MB, L2-resident).
__global__ __launch_bounds__(64) void proj_tgt_kernel(
    const float* __restrict__ h_tgt, const float* __restrict__ W,
    float* __restrict__ u_part)
{
    const int lane = (int)threadIdx.x;
    const int b0   = (int)blockIdx.x * BG;
    const int slot = (int)blockIdx.y * 64 + lane;    // float4 slot in [0,250)
    const int p    = (int)blockIdx.z;                // g-split
    const bool ok  = (slot < Hh / 4);
    const int h    = slot * 4;

    v4f acc[BG];
    #pragma unroll
    for (int bi = 0; bi < BG; ++bi) acc[bi] = (v4f){0.f, 0.f, 0.f, 0.f};

    const float* wp = W + (size_t)(p * GL) * Hh + h;
    const int gbase = p * GL;
    #pragma unroll 4
    for (int g = 0; g < GL; ++g) {
        const v4f w4 = ok ? *(const v4f*)wp : (v4f){0.f, 0.f, 0.f, 0.f};
        #pragma unroll
        for (int bi = 0; bi < BG; ++bi) {
            const float a = h_tgt[(b0 + bi) * Hh + gbase + g];  // wave-uniform s_load
            acc[bi] += a * w4;
        }
        wp += Hh;
    }
    if (ok) {
        #pragma unroll
        for (int bi = 0; bi < BG; ++bi)
            *(v4f*)(u_part + (size_t)(p * Bb + b0 + bi) * Hh + h) = acc[bi];
    }
}

// Kernel 1b: u = sum_p u_part[p]. 64000 floats, all L2.
__global__ __launch_bounds__(256) void ureduce_kernel(
    const float* __restrict__ u_part, float* __restrict__ u)
{
    const int i = (int)(blockIdx.x * blockDim.x + threadIdx.x);  // float4 slot
    if (i < Bb * Hh / 4) {
        v4f s = (v4f){0.f, 0.f, 0.f, 0.f};
        #pragma unroll
        for (int p = 0; p < GS; ++p)
            s += *(const v4f*)(u_part + (size_t)p * Bb * Hh + i * 4);
        *(v4f*)(u + i * 4) = s;
    }
}

// Kernel 2: fused score + online softmax + weighted accumulation.
// One wave per (b, s-chunk of 16); 4096 waves. h_src read once, nontemporal.
__global__ __launch_bounds__(256) void attn_partial_kernel(
    const float* __restrict__ h_src, const float* __restrict__ u,
    float* __restrict__ wsM, float* __restrict__ wsL, float* __restrict__ wsC)
{
    const int lane  = threadIdx.x & 63;
    const int wave  = (int)((blockIdx.x * blockDim.x + threadIdx.x) >> 6);
    const int b     = wave >> 6;      // / CHUNKS
    const int chunk = wave & 63;      // % CHUNKS
    const int s0    = chunk * CS;

    const float* ub = u + b * Hh;
    v4f uf[4];
    #pragma unroll
    for (int j = 0; j < 4; ++j) {
        const int d = j * 256 + lane * 4;
        uf[j] = (d < Hh) ? *(const v4f*)(ub + d) : (v4f){0.f, 0.f, 0.f, 0.f};
    }

    float m = -INFINITY, l = 0.f;
    v4f c[4];
    #pragma unroll
    for (int j = 0; j < 4; ++j) c[j] = (v4f){0.f, 0.f, 0.f, 0.f};

    const float* xp = h_src + (size_t)(b * Ss + s0) * Hh;
    #pragma unroll 2
    for (int s = 0; s < CS; s += 2) {
        v4f x0[4], x1[4];
        #pragma unroll
        for (int j = 0; j < 4; ++j) {
            const int d = j * 256 + lane * 4;
            x0[j] = (d < Hh) ? __builtin_nontemporal_load((const v4f*)(xp + d))
                             : (v4f){0.f, 0.f, 0.f, 0.f};
            x1[j] = (d < Hh) ? __builtin_nontemporal_load((const v4f*)(xp + Hh + d))
                             : (v4f){0.f, 0.f, 0.f, 0.f};
        }
        float p0 = 0.f, p1 = 0.f;
        #pragma unroll
        for (int j = 0; j < 4; ++j) {
            p0 = fmaf(x0[j].x, uf[j].x, p0); p0 = fmaf(x0[j].y, uf[j].y, p0);
            p0 = fmaf(x0[j].z, uf[j].z, p0); p0 = fmaf(x0[j].w, uf[j].w, p0);
            p1 = fmaf(x1[j].x, uf[j].x, p1); p1 = fmaf(x1[j].y, uf[j].y, p1);
            p1 = fmaf(x1[j].z, uf[j].z, p1); p1 = fmaf(x1[j].w, uf[j].w, p1);
        }
        #pragma unroll
        for (int off = 32; off > 0; off >>= 1) {
            p0 += __shfl_xor(p0, off, 64);
            p1 += __shfl_xor(p1, off, 64);
        }
        const float sc0 = p0, sc1 = p1;

        const float mn = fmaxf(m, fmaxf(sc0, sc1));
        if (mn > m) {                            // wave-uniform branch
            const float scale = __expf(m - mn);  // first iter: exp(-inf)=0
            m = mn;
            l *= scale;
            #pragma unroll
            for (int j = 0; j < 4; ++j) c[j] *= scale;
        }
        const float e0 = __expf(sc0 - m);
        const float e1 = __expf(sc1 - m);
        l += e0 + e1;
        #pragma unroll
        for (int j = 0; j < 4; ++j) {
            c[j].x = fmaf(e0, x0[j].x, fmaf(e1, x1[j].x, c[j].x));
            c[j].y = fmaf(e0, x0[j].y, fmaf(e1, x1[j].y, c[j].y));
            c[j].z = fmaf(e0, x0[j].z, fmaf(e1, x1[j].z, c[j].z));
            c[j].w = fmaf(e0, x0[j].w, fmaf(e1, x1[j].w, c[j].w));
        }
        xp += 2 * Hh;
    }

    const int idx = b * CHUNKS + chunk;
    if (lane == 0) { wsM[idx] = m; wsL[idx] = l; }
    float* cw = wsC + (size_t)idx * Hh;
    #pragma unroll
    for (int j = 0; j < 4; ++j) {
        const int d = j * 256 + lane * 4;
        if (d < Hh) *(v4f*)(cw + d) = c[j];   // cached: combine re-reads from L2
    }
}

// Kernel 3: merge 64 chunk-partials per batch. Grid (64 b, 4 h-quarters).
__global__ __launch_bounds__(256) void combine_kernel(
    const float* __restrict__ wsM, const float* __restrict__ wsL,
    const float* __restrict__ wsC, float* __restrict__ out)
{
    const int b   = blockIdx.x;
    const int tid = (int)threadIdx.x;
    __shared__ float sw[CHUNKS];
    __shared__ float sInvL;

    if (tid < 64) {   // wave 0: lane = chunk
        const float mi = wsM[b * CHUNKS + tid];
        const float li = wsL[b * CHUNKS + tid];
        float M = mi;
        #pragma unroll
        for (int off = 32; off > 0; off >>= 1) M = fmaxf(M, __shfl_xor(M, off, 64));
        const float w = __expf(mi - M);
        float L = w * li;
        #pragma unroll
        for (int off = 32; off > 0; off >>= 1) L += __shfl_xor(L, off, 64);
        sw[tid] = w;
        if (tid == 0) sInvL = 1.f / L;
    }
    __syncthreads();

    const int h = blockIdx.y * 250 + tid;
    if (tid < 250) {
        float acc = 0.f;
        #pragma unroll 8
        for (int i = 0; i < CHUNKS; ++i)
            acc = fmaf(sw[i], wsC[(size_t)(b * CHUNKS + i) * Hh + h], acc);
        out[b * Hh + h] = acc * sInvL;
    }
}

extern "C" void kernel_launch(void* const* d_in, const int* in_sizes, int n_in,
                              void* d_out, int out_size, void* d_ws, size_t ws_size,
                              hipStream_t stream) {
    const float* h_tgt = (const float*)d_in[0];
    const float* h_src = (const float*)d_in[1];
    const float* W     = (const float*)d_in[2];
    // bias (d_in[3]) unused: h_tgt . bias is constant over s -> cancels in softmax.
    float* out = (float*)d_out;

    // ws floats: u[64000] | wsM[4096] | wsL[4096] | wsC[4096000] | u_part[512000]
    float* u      = (float*)d_ws;
    float* wsM    = u + Bb * Hh;
    float* wsL    = wsM + Bb * CHUNKS;
    float* wsC    = wsL + Bb * CHUNKS;          // float offset 72192 (16B aligned)
    float* u_part = wsC + (size_t)Bb * CHUNKS * Hh;

    proj_tgt_kernel<<<dim3(Bb / BG, 4, GS), 64, 0, stream>>>(h_tgt, W, u_part);
    ureduce_kernel<<<(Bb * Hh / 4 + 255) / 256, 256, 0, stream>>>(u_part, u);
    attn_partial_kernel<<<(Bb * CHUNKS) / 4, 256, 0, stream>>>(h_src, u, wsM, wsL, wsC);
    combine_kernel<<<dim3(Bb, 4), 256, 0, stream>>>(wsM, wsL, wsC, out);
}

// Round 4
// 378.509 us; speedup vs baseline: 1.1576x; 1.0118x over previous
//
#include <hip/hip_runtime.h>

typedef float v4f __attribute__((ext_vector_type(4)));

// Problem constants: B=64, S=1024, H=1000.
constexpr int Bb = 64;
constexpr int Ss = 1024;
constexpr int Hh = 1000;
constexpr int CHUNKS = 32;          // s-chunks per batch (one wave each)
constexpr int CS = Ss / CHUNKS;     // 32 positions per wave
constexpr int BG = 4;               // batches per proj block
constexpr int GS = 8;               // g-splits for proj
constexpr int GL = Hh / GS;         // 125 g per split

// Kernel 1a: partial u. Grid (16 b-groups, 4 slot-groups, 8 g-splits) x 64 thr.
__global__ __launch_bounds__(64) void proj_tgt_kernel(
    const float* __restrict__ h_tgt, const float* __restrict__ W,
    float* __restrict__ u_part)
{
    const int lane = (int)threadIdx.x;
    const int b0   = (int)blockIdx.x * BG;
    const int slot = (int)blockIdx.y * 64 + lane;    // float4 slot in [0,250)
    const int p    = (int)blockIdx.z;                // g-split
    const bool ok  = (slot < Hh / 4);
    const int h    = slot * 4;

    v4f acc[BG];
    #pragma unroll
    for (int bi = 0; bi < BG; ++bi) acc[bi] = (v4f){0.f, 0.f, 0.f, 0.f};

    const float* wp = W + (size_t)(p * GL) * Hh + h;
    const int gbase = p * GL;
    #pragma unroll 4
    for (int g = 0; g < GL; ++g) {
        const v4f w4 = ok ? *(const v4f*)wp : (v4f){0.f, 0.f, 0.f, 0.f};
        #pragma unroll
        for (int bi = 0; bi < BG; ++bi) {
            const float a = h_tgt[(b0 + bi) * Hh + gbase + g];  // wave-uniform s_load
            acc[bi] += a * w4;
        }
        wp += Hh;
    }
    if (ok) {
        #pragma unroll
        for (int bi = 0; bi < BG; ++bi)
            *(v4f*)(u_part + (size_t)(p * Bb + b0 + bi) * Hh + h) = acc[bi];
    }
}

// Kernel 1b: u = sum_p u_part[p]. 64000 floats, all L2.
__global__ __launch_bounds__(256) void ureduce_kernel(
    const float* __restrict__ u_part, float* __restrict__ u)
{
    const int i = (int)(blockIdx.x * blockDim.x + threadIdx.x);  // float4 slot
    if (i < Bb * Hh / 4) {
        v4f s = (v4f){0.f, 0.f, 0.f, 0.f};
        #pragma unroll
        for (int p = 0; p < GS; ++p)
            s += *(const v4f*)(u_part + (size_t)p * Bb * Hh + i * 4);
        *(v4f*)(u + i * 4) = s;
    }
}

// Kernel 2: fused score + online softmax + weighted accumulation.
// One wave per (b, s-chunk of 32); 2048 waves (8/CU). 4 s-rows per macro-iter
// -> 16 dwordx4 loads in flight per wave, 4 interleaved shuffle/exp chains.
__global__ __launch_bounds__(256) void attn_partial_kernel(
    const float* __restrict__ h_src, const float* __restrict__ u,
    float* __restrict__ wsM, float* __restrict__ wsL, float* __restrict__ wsC)
{
    const int lane  = threadIdx.x & 63;
    const int wave  = (int)((blockIdx.x * blockDim.x + threadIdx.x) >> 6);
    const int b     = wave >> 5;      // / CHUNKS
    const int chunk = wave & 31;      // % CHUNKS
    const int s0    = chunk * CS;

    const float* ub = u + b * Hh;
    v4f uf[4];
    #pragma unroll
    for (int j = 0; j < 4; ++j) {
        const int d = j * 256 + lane * 4;
        uf[j] = (d < Hh) ? *(const v4f*)(ub + d) : (v4f){0.f, 0.f, 0.f, 0.f};
    }

    float m = -INFINITY, l = 0.f;
    v4f c[4];
    #pragma unroll
    for (int j = 0; j < 4; ++j) c[j] = (v4f){0.f, 0.f, 0.f, 0.f};

    const float* xp = h_src + (size_t)(b * Ss + s0) * Hh;
    for (int s = 0; s < CS; s += 4) {
        v4f x[4][4];                  // [row][j]
        #pragma unroll
        for (int r = 0; r < 4; ++r) {
            #pragma unroll
            for (int j = 0; j < 4; ++j) {
                const int d = j * 256 + lane * 4;
                x[r][j] = (d < Hh)
                    ? __builtin_nontemporal_load((const v4f*)(xp + (size_t)r * Hh + d))
                    : (v4f){0.f, 0.f, 0.f, 0.f};
            }
        }
        float p[4] = {0.f, 0.f, 0.f, 0.f};
        #pragma unroll
        for (int r = 0; r < 4; ++r) {
            #pragma unroll
            for (int j = 0; j < 4; ++j) {
                p[r] = fmaf(x[r][j].x, uf[j].x, p[r]);
                p[r] = fmaf(x[r][j].y, uf[j].y, p[r]);
                p[r] = fmaf(x[r][j].z, uf[j].z, p[r]);
                p[r] = fmaf(x[r][j].w, uf[j].w, p[r]);
            }
        }
        // four interleaved 64-lane butterflies
        #pragma unroll
        for (int off = 32; off > 0; off >>= 1) {
            #pragma unroll
            for (int r = 0; r < 4; ++r) p[r] += __shfl_xor(p[r], off, 64);
        }

        const float mx01 = fmaxf(p[0], p[1]);
        const float mx23 = fmaxf(p[2], p[3]);
        const float mn = fmaxf(m, fmaxf(mx01, mx23));
        if (mn > m) {                            // wave-uniform branch
            const float scale = __expf(m - mn);  // first iter: exp(-inf)=0
            m = mn;
            l *= scale;
            #pragma unroll
            for (int j = 0; j < 4; ++j) c[j] *= scale;
        }
        float e[4];
        #pragma unroll
        for (int r = 0; r < 4; ++r) e[r] = __expf(p[r] - m);
        l += (e[0] + e[1]) + (e[2] + e[3]);
        #pragma unroll
        for (int r = 0; r < 4; ++r) {
            #pragma unroll
            for (int j = 0; j < 4; ++j) {
                c[j].x = fmaf(e[r], x[r][j].x, c[j].x);
                c[j].y = fmaf(e[r], x[r][j].y, c[j].y);
                c[j].z = fmaf(e[r], x[r][j].z, c[j].z);
                c[j].w = fmaf(e[r], x[r][j].w, c[j].w);
            }
        }
        xp += 4 * Hh;
    }

    const int idx = b * CHUNKS + chunk;
    if (lane == 0) { wsM[idx] = m; wsL[idx] = l; }
    float* cw = wsC + (size_t)idx * Hh;
    #pragma unroll
    for (int j = 0; j < 4; ++j) {
        const int d = j * 256 + lane * 4;
        if (d < Hh) *(v4f*)(cw + d) = c[j];   // cached: combine re-reads from L2
    }
}

// Kernel 3: merge 32 chunk-partials per batch. Grid (64). v4f reads of wsC.
__global__ __launch_bounds__(256) void combine_kernel(
    const float* __restrict__ wsM, const float* __restrict__ wsL,
    const float* __restrict__ wsC, float* __restrict__ out)
{
    const int b   = blockIdx.x;
    const int tid = (int)threadIdx.x;
    __shared__ float sw[CHUNKS];
    __shared__ float sInvL;

    if (tid < 64) {   // wave 0: lanes 0..31 = chunks, 32..63 neutral
        const bool v = (tid < CHUNKS);
        const float mi = v ? wsM[b * CHUNKS + tid] : -INFINITY;
        const float li = v ? wsL[b * CHUNKS + tid] : 0.f;
        float M = mi;
        #pragma unroll
        for (int off = 32; off > 0; off >>= 1) M = fmaxf(M, __shfl_xor(M, off, 64));
        const float w = __expf(mi - M);
        float L = w * li;
        #pragma unroll
        for (int off = 32; off > 0; off >>= 1) L += __shfl_xor(L, off, 64);
        if (v) sw[tid] = w;
        if (tid == 0) sInvL = 1.f / L;
    }
    __syncthreads();

    const int h = tid * 4;            // 250 active float4 slots
    if (h < Hh) {
        v4f acc = (v4f){0.f, 0.f, 0.f, 0.f};
        #pragma unroll 8
        for (int i = 0; i < CHUNKS; ++i)
            acc += sw[i] * *(const v4f*)(wsC + (size_t)(b * CHUNKS + i) * Hh + h);
        *(v4f*)(out + b * Hh + h) = acc * sInvL;
    }
}

extern "C" void kernel_launch(void* const* d_in, const int* in_sizes, int n_in,
                              void* d_out, int out_size, void* d_ws, size_t ws_size,
                              hipStream_t stream) {
    const float* h_tgt = (const float*)d_in[0];
    const float* h_src = (const float*)d_in[1];
    const float* W     = (const float*)d_in[2];
    // bias (d_in[3]) unused: h_tgt . bias is constant over s -> cancels in softmax.
    float* out = (float*)d_out;

    // ws floats: u[64000] | wsM[2048] | wsL[2048] | wsC[2048000] | u_part[512000]
    float* u      = (float*)d_ws;
    float* wsM    = u + Bb * Hh;
    float* wsL    = wsM + Bb * CHUNKS;
    float* wsC    = wsL + Bb * CHUNKS;          // float offset 68096 (16B aligned)
    float* u_part = wsC + (size_t)Bb * CHUNKS * Hh;

    proj_tgt_kernel<<<dim3(Bb / BG, 4, GS), 64, 0, stream>>>(h_tgt, W, u_part);
    ureduce_kernel<<<(Bb * Hh / 4 + 255) / 256, 256, 0, stream>>>(u_part, u);
    attn_partial_kernel<<<(Bb * CHUNKS) / 4, 256, 0, stream>>>(h_src, u, wsM, wsL, wsC);
    combine_kernel<<<Bb, 256, 0, stream>>>(wsM, wsL, wsC, out);
}